// Round 1
// baseline (7300.525 us; speedup 1.0000x reference)
//
#include <hip/hip_runtime.h>

#define T_DIM 512
#define B_DIM 64
#define I_DIM 512
#define H_DIM 512
#define BH (B_DIM * H_DIM)              // 32768
#define TBH ((size_t)T_DIM * BH)        // 16777216

typedef __attribute__((ext_vector_type(8))) short short8;
typedef __attribute__((ext_vector_type(4))) float f32x4;

__device__ __forceinline__ unsigned short f2bf(float x) {
    unsigned int u = __float_as_uint(x);
    u = u + 0x7FFFu + ((u >> 16) & 1u);
    return (unsigned short)(u >> 16);
}
__device__ __forceinline__ float bf2f(unsigned short s) {
    return __uint_as_float(((unsigned int)s) << 16);
}
// split 8 floats into hi/lo bf16 fragments (bf16x3 trick: x ~= hi + lo)
__device__ __forceinline__ void packhl(const float* f, short8& hi, short8& lo) {
#pragma unroll
    for (int i = 0; i < 8; i++) {
        unsigned short h = f2bf(f[i]);
        hi[i] = (short)h;
        lo[i] = (short)f2bf(f[i] - bf2f(h));
    }
}

__device__ __forceinline__ float gload(const float* p) {
    return __hip_atomic_load((float*)p, __ATOMIC_RELAXED, __HIP_MEMORY_SCOPE_AGENT);
}
__device__ __forceinline__ void gstore(float* p, float v) {
    __hip_atomic_store(p, v, __ATOMIC_RELAXED, __HIP_MEMORY_SCOPE_AGENT);
}

// ---------------------------------------------------------------------------
// Kernel X: xz/xr = input . zt_w_w / rt_w_w (+ biases); also zeroes barriers.
// One wave per (t,b) row. 8192 blocks x 256 threads.
// ---------------------------------------------------------------------------
__global__ __launch_bounds__(256) void xzr_kernel(
    const float* __restrict__ input,
    const float* __restrict__ zw, const float* __restrict__ zb,
    const float* __restrict__ rw, const float* __restrict__ rb,
    float* __restrict__ xz, float* __restrict__ xr,
    unsigned int* __restrict__ bar)
{
    const int tid = threadIdx.x, bx = blockIdx.x;
    if (bx < 32) {
#pragma unroll
        for (int i = 0; i < 8; i++) bar[(bx * 256 + tid) + i * 8192] = 0u;
    }
    const int row = bx * 4 + (tid >> 6);
    const int lane = tid & 63;
    const float* p = input + (size_t)row * I_DIM + lane * 8;
    float x[8], z[8], r[8];
    *(float4*)(x)     = *(const float4*)(p);
    *(float4*)(x + 4) = *(const float4*)(p + 4);
    *(float4*)(z)     = *(const float4*)(zw + lane * 8);
    *(float4*)(z + 4) = *(const float4*)(zw + lane * 8 + 4);
    *(float4*)(r)     = *(const float4*)(rw + lane * 8);
    *(float4*)(r + 4) = *(const float4*)(rw + lane * 8 + 4);
    float pz = 0.f, pr = 0.f;
#pragma unroll
    for (int i = 0; i < 8; i++) { pz += x[i] * z[i]; pr += x[i] * r[i]; }
#pragma unroll
    for (int off = 32; off > 0; off >>= 1) {
        pz += __shfl_xor(pz, off);
        pr += __shfl_xor(pr, off);
    }
    if (lane == 0) {
        xz[row] = pz + zb[0];
        xr[row] = pr + rb[0];
    }
}

// ---------------------------------------------------------------------------
// Kernel A: xn = input @ h_w_w^T + h_w_b  -> stored into d_out[0..TBH)
// bf16x3 MFMA, 64x64 tiles, BK=32. 4096 blocks x 256 threads.
// ---------------------------------------------------------------------------
#define APITCH 40  // bf16 pitch: 80B rows, 16B aligned, 2-way bank aliasing (free)

__global__ __launch_bounds__(256, 2) void xn_gemm_kernel(
    const float* __restrict__ A, const float* __restrict__ W,
    const float* __restrict__ bias, float* __restrict__ C)
{
    __shared__ __align__(16) unsigned short a_hi[64 * APITCH], a_lo[64 * APITCH];
    __shared__ __align__(16) unsigned short b_hi[64 * APITCH], b_lo[64 * APITCH];
    const int tid = threadIdx.x;
    const int bx = blockIdx.x;
    const int mt = bx >> 3, ntile = bx & 7;
    const int wv = tid >> 6, lane = tid & 63;
    const int srow = tid >> 2, skseg = (tid & 3) * 8;
    const int m = lane & 15;
    const int ko = (lane >> 4) * 8;

    f32x4 ahh[4], ahl[4], alh[4];
#pragma unroll
    for (int i = 0; i < 4; i++) { ahh[i] = (f32x4)0.f; ahl[i] = (f32x4)0.f; alh[i] = (f32x4)0.f; }

    for (int kt = 0; kt < 16; ++kt) {
        {
            float fa[8], fb[8];
            const float* pa = A + (size_t)(mt * 64 + srow) * I_DIM + kt * 32 + skseg;
            *(float4*)(fa)     = *(const float4*)(pa);
            *(float4*)(fa + 4) = *(const float4*)(pa + 4);
            const float* pb = W + (size_t)(ntile * 64 + srow) * I_DIM + kt * 32 + skseg;
            *(float4*)(fb)     = *(const float4*)(pb);
            *(float4*)(fb + 4) = *(const float4*)(pb + 4);
            short8 hi, lo;
            packhl(fa, hi, lo);
            *(short8*)&a_hi[srow * APITCH + skseg] = hi;
            *(short8*)&a_lo[srow * APITCH + skseg] = lo;
            packhl(fb, hi, lo);
            *(short8*)&b_hi[srow * APITCH + skseg] = hi;
            *(short8*)&b_lo[srow * APITCH + skseg] = lo;
        }
        __syncthreads();
        short8 vah = *(const short8*)&a_hi[(wv * 16 + m) * APITCH + ko];
        short8 val = *(const short8*)&a_lo[(wv * 16 + m) * APITCH + ko];
#pragma unroll
        for (int ns = 0; ns < 4; ++ns) {
            short8 vbh = *(const short8*)&b_hi[(ns * 16 + m) * APITCH + ko];
            short8 vbl = *(const short8*)&b_lo[(ns * 16 + m) * APITCH + ko];
            ahh[ns] = __builtin_amdgcn_mfma_f32_16x16x32_bf16(vah, vbh, ahh[ns], 0, 0, 0);
            ahl[ns] = __builtin_amdgcn_mfma_f32_16x16x32_bf16(vah, vbl, ahl[ns], 0, 0, 0);
            alh[ns] = __builtin_amdgcn_mfma_f32_16x16x32_bf16(val, vbh, alh[ns], 0, 0, 0);
        }
        __syncthreads();
    }
#pragma unroll
    for (int ns = 0; ns < 4; ++ns) {
#pragma unroll
        for (int rr = 0; rr < 4; ++rr) {
            int rowd = wv * 16 + (lane >> 4) * 4 + rr;
            int cold = ntile * 64 + ns * 16 + (lane & 15);
            float v = ahh[ns][rr] + ahl[ns][rr] + alh[ns][rr] + bias[cold];
            C[(size_t)(mt * 64 + rowd) * H_DIM + cold] = v;
        }
    }
}

// ---------------------------------------------------------------------------
// Recurrent persistent kernel. 32 WGs = 4 batch-groups (16 rows) x 8 col
// slices (64 cols). Per group-of-8 sub-barrier each step (per-step counters).
// h exchange via agent-scope coherent loads/stores; xn read from d_out and
// overwritten in-place by h_t. Weights live in VGPRs as bf16 hi/lo frags.
// ---------------------------------------------------------------------------
#define NG 4
#define NJ 8
#define HP 516  // f32 LDS pitch: 16B-aligned rows, 2-way bank aliasing (free)

__global__ __launch_bounds__(256, 1) void rnn_kernel(
    const float* __restrict__ h0,
    const float* __restrict__ xz, const float* __restrict__ xr,
    const float* __restrict__ zuw, const float* __restrict__ ruw,
    const float* __restrict__ zub, const float* __restrict__ rub,
    const float* __restrict__ huw, const float* __restrict__ hub,
    float* __restrict__ out, unsigned int* __restrict__ bar)
{
    __shared__ float hs[16 * HP];
    __shared__ float zu[512], ru[512];
    __shared__ float zg[16], rg[16];
    const int tid = threadIdx.x;
    const int wg = blockIdx.x;
    const int g = wg >> 3, js = wg & 7;
    const int wv = tid >> 6, lane = tid & 63;

    for (int i = tid; i < 512; i += 256) { zu[i] = zuw[i]; ru[i] = ruw[i]; }
    const float zbias = zub[0], rbias = rub[0];

    const int col = js * 64 + wv * 16 + (lane & 15);
    const int ko = (lane >> 4) * 8;
    const int am = lane & 15;

    // persistent recurrent-weight fragments (B operand), hi/lo bf16
    short8 wh[16], wl[16];
#pragma unroll
    for (int kt = 0; kt < 16; ++kt) {
        float f[8];
        const float* p = huw + (size_t)col * H_DIM + kt * 32 + ko;
        *(float4*)(f)     = *(const float4*)(p);
        *(float4*)(f + 4) = *(const float4*)(p + 4);
        packhl(f, wh[kt], wl[kt]);
    }
    const float hubl = hub[col];
    const int gr = tid >> 4, gs = tid & 15;
    __syncthreads();

    float hkeep[4] = {0.f, 0.f, 0.f, 0.f};

    for (int t = 0; t < T_DIM; ++t) {
        const float* hp = (t == 0) ? (h0 + g * 16 * H_DIM)
                                   : (out + (size_t)(t - 1) * BH + g * 16 * H_DIM);
        // coherent load of this group's 16x512 h block into LDS
#pragma unroll
        for (int i = 0; i < 32; i++) {
            int idx = tid + i * 256;
            int r_ = idx >> 9, k_ = idx & 511;
            hs[r_ * HP + k_] = gload(hp + r_ * H_DIM + k_);
        }
        __syncthreads();

        // gates zt/rt for the 16 rows (replicated per WG; cheap)
        float pz = 0.f, pr = 0.f;
#pragma unroll
        for (int i = 0; i < 8; i++) {
            int k4 = i * 64 + gs * 4;
            float4 hv = *(const float4*)&hs[gr * HP + k4];
            float4 zv = *(const float4*)&zu[k4];
            float4 rv = *(const float4*)&ru[k4];
            pz += hv.x * zv.x + hv.y * zv.y + hv.z * zv.z + hv.w * zv.w;
            pr += hv.x * rv.x + hv.y * rv.y + hv.z * rv.z + hv.w * rv.w;
        }
#pragma unroll
        for (int off = 8; off > 0; off >>= 1) {
            pz += __shfl_xor(pz, off);
            pr += __shfl_xor(pr, off);
        }
        if (gs == 0) {
            int b_ = g * 16 + gr;
            zg[gr] = 1.f / (1.f + __expf(-(xz[t * B_DIM + b_] + pz + zbias)));
            rg[gr] = 1.f / (1.f + __expf(-(xr[t * B_DIM + b_] + pr + rbias)));
        }
        __syncthreads();

        // h @ h_u_w^T slice via bf16x3 MFMA
        f32x4 hh = (f32x4)0.f, hl = (f32x4)0.f, lh = (f32x4)0.f;
#pragma unroll
        for (int kt = 0; kt < 16; ++kt) {
            float f[8];
            const float* p = &hs[am * HP + kt * 32 + ko];
            *(float4*)(f)     = *(const float4*)(p);
            *(float4*)(f + 4) = *(const float4*)(p + 4);
            short8 ah, al;
            packhl(f, ah, al);
            hh = __builtin_amdgcn_mfma_f32_16x16x32_bf16(ah, wh[kt], hh, 0, 0, 0);
            hl = __builtin_amdgcn_mfma_f32_16x16x32_bf16(ah, wl[kt], hl, 0, 0, 0);
            lh = __builtin_amdgcn_mfma_f32_16x16x32_bf16(al, wh[kt], lh, 0, 0, 0);
        }

        // epilogue: gates + tanh + blend; overwrite xn[t] with h_t
        float* op = out + (size_t)t * BH;
#pragma unroll
        for (int rr = 0; rr < 4; ++rr) {
            int rl = (lane >> 4) * 4 + rr;
            int b_ = g * 16 + rl;
            float gemm = hh[rr] + hl[rr] + lh[rr] + hubl;
            float xnv = op[(size_t)b_ * H_DIM + col];  // xn written by kernel A
            float z = zg[rl], rt_ = rg[rl];
            float x2 = xnv + gemm * rt_;
            x2 = fminf(fmaxf(x2, -30.f), 30.f);
            float e = __expf(2.f * x2);
            float ntv = (e - 1.f) / (e + 1.f);
            float hold = hs[rl * HP + col];
            float hv = (1.f - z) * ntv + z * hold;
            gstore(op + (size_t)b_ * H_DIM + col, hv);
            hkeep[rr] = hv;
        }
        __syncthreads();
        if (tid == 0) {
            unsigned int* c = bar + ((size_t)t * NG + g) * 32;
            __hip_atomic_fetch_add(c, 1u, __ATOMIC_RELEASE, __HIP_MEMORY_SCOPE_AGENT);
            while (__hip_atomic_load(c, __ATOMIC_ACQUIRE, __HIP_MEMORY_SCOPE_AGENT) < NJ)
                __builtin_amdgcn_s_sleep(1);
        }
        __syncthreads();
    }

    // hidden_final = h at t = T-1
#pragma unroll
    for (int rr = 0; rr < 4; ++rr) {
        int rl = (lane >> 4) * 4 + rr;
        int b_ = g * 16 + rl;
        out[TBH + (size_t)b_ * H_DIM + col] = hkeep[rr];
    }
}

extern "C" void kernel_launch(void* const* d_in, const int* in_sizes, int n_in,
                              void* d_out, int out_size, void* d_ws, size_t ws_size,
                              hipStream_t stream)
{
    const float* input  = (const float*)d_in[0];
    const float* hidden = (const float*)d_in[1];
    const float* zt_w_w = (const float*)d_in[2];
    const float* zt_w_b = (const float*)d_in[3];
    const float* zt_u_w = (const float*)d_in[4];
    const float* zt_u_b = (const float*)d_in[5];
    const float* rt_w_w = (const float*)d_in[6];
    const float* rt_w_b = (const float*)d_in[7];
    const float* rt_u_w = (const float*)d_in[8];
    const float* rt_u_b = (const float*)d_in[9];
    const float* h_w_w  = (const float*)d_in[10];
    const float* h_w_b  = (const float*)d_in[11];
    const float* h_u_w  = (const float*)d_in[12];
    const float* h_u_b  = (const float*)d_in[13];
    float* out = (float*)d_out;

    // ws layout: [0,256K) barrier counters, [256K,384K) xz, [384K,512K) xr
    unsigned int* bar = (unsigned int*)d_ws;
    float* xz = (float*)((char*)d_ws + 262144);
    float* xr = (float*)((char*)d_ws + 262144 + 131072);

    xzr_kernel<<<dim3(8192), dim3(256), 0, stream>>>(input, zt_w_w, zt_w_b,
                                                     rt_w_w, rt_w_b, xz, xr, bar);
    xn_gemm_kernel<<<dim3(4096), dim3(256), 0, stream>>>(input, h_w_w, h_w_b, out);
    rnn_kernel<<<dim3(32), dim3(256), 0, stream>>>(hidden, xz, xr, zt_u_w, rt_u_w,
                                                   zt_u_b, rt_u_b, h_u_w, h_u_b,
                                                   out, bar);
}

// Round 3
// 2373.844 us; speedup vs baseline: 3.0754x; 3.0754x over previous
//
#include <hip/hip_runtime.h>
#include <hip/hip_fp16.h>

#define T_DIM 512
#define B_DIM 64
#define I_DIM 512
#define H_DIM 512
#define BH (B_DIM * H_DIM)              // 32768
#define TBH ((size_t)T_DIM * BH)        // 16777216

typedef __attribute__((ext_vector_type(8))) short short8;
typedef __attribute__((ext_vector_type(4))) float f32x4;

// LDS swizzle for 16x512 ushort planes: keeps 8-ushort (16B) blocks intact,
// spreads banks evenly across rows for both MFMA-frag and gate access.
#define SW16(r, k) ((r) * 512 + ((k) ^ (((r) & 15) << 3)))

__device__ __forceinline__ unsigned short f2bf(float x) {
    unsigned int u = __float_as_uint(x);
    u = u + 0x7FFFu + ((u >> 16) & 1u);
    return (unsigned short)(u >> 16);
}
__device__ __forceinline__ float bf2f(unsigned short s) {
    return __uint_as_float(((unsigned int)s) << 16);
}
__device__ __forceinline__ float uasf(unsigned int u) { return __uint_as_float(u); }

// --- inline-asm memory helpers -------------------------------------------
// coherent (device-scope) 16B load: bypasses L1+L2 per-access, NO flushes
__device__ __forceinline__ void ld128_coh(uint4& d, const void* p) {
    asm volatile("global_load_dwordx4 %0, %1, off sc0 sc1"
                 : "=v"(d) : "v"(p) : "memory");
}
// same, but drains ALL outstanding vector loads afterwards (vmcnt counts
// the whole wave's queue). NOTE: gfx950 inline asm rejects tied 128-bit
// operands, so the waitcnt must live inside a load asm, not standalone.
__device__ __forceinline__ void ld128_coh_wait(uint4& d, const void* p) {
    asm volatile("global_load_dwordx4 %0, %1, off sc0 sc1\n\t"
                 "s_waitcnt vmcnt(0)"
                 : "=v"(d) : "v"(p) : "memory");
}
// plain cached loads (cross-dispatch data: xn, xz/xr)
__device__ __forceinline__ void ld32f(float& d, const void* p) {
    asm volatile("global_load_dword %0, %1, off" : "=v"(d) : "v"(p));
}
__device__ __forceinline__ void ld32u(unsigned int& d, const void* p) {
    asm volatile("global_load_dword %0, %1, off" : "=v"(d) : "v"(p));
}

// ---------------------------------------------------------------------------
// Kernel X: xz/xr input projections -> packed f16 pair per (t,b).
// Also zeroes the flag array (runs before rnn on the same stream).
// ---------------------------------------------------------------------------
__global__ __launch_bounds__(256) void xzr_kernel(
    const float* __restrict__ input,
    const float* __restrict__ zw, const float* __restrict__ zb,
    const float* __restrict__ rw, const float* __restrict__ rb,
    unsigned int* __restrict__ xzr, unsigned int* __restrict__ flags)
{
    const int tid = threadIdx.x, bx = blockIdx.x;
    if (bx == 0 && tid < 32) flags[tid] = 0u;
    const int row = bx * 4 + (tid >> 6);
    const int lane = tid & 63;
    const float* p = input + (size_t)row * I_DIM + lane * 8;
    float x[8], z[8], r[8];
    *(float4*)(x)     = *(const float4*)(p);
    *(float4*)(x + 4) = *(const float4*)(p + 4);
    *(float4*)(z)     = *(const float4*)(zw + lane * 8);
    *(float4*)(z + 4) = *(const float4*)(zw + lane * 8 + 4);
    *(float4*)(r)     = *(const float4*)(rw + lane * 8);
    *(float4*)(r + 4) = *(const float4*)(rw + lane * 8 + 4);
    float pz = 0.f, pr = 0.f;
#pragma unroll
    for (int i = 0; i < 8; i++) { pz += x[i] * z[i]; pr += x[i] * r[i]; }
#pragma unroll
    for (int off = 32; off > 0; off >>= 1) {
        pz += __shfl_xor(pz, off);
        pr += __shfl_xor(pr, off);
    }
    if (lane == 0) {
        unsigned int uz = __half_as_ushort(__float2half(pz + zb[0]));
        unsigned int ur = __half_as_ushort(__float2half(pr + rb[0]));
        xzr[row] = (uz << 16) | ur;
    }
}

// ---------------------------------------------------------------------------
// Kernel A: xn = input @ h_w_w^T + h_w_b -> d_out[0..TBH)
// ---------------------------------------------------------------------------
#define APITCH 40

__global__ __launch_bounds__(256, 2) void xn_gemm_kernel(
    const float* __restrict__ A, const float* __restrict__ W,
    const float* __restrict__ bias, float* __restrict__ C)
{
    __shared__ __align__(16) unsigned short a_hi[64 * APITCH], a_lo[64 * APITCH];
    __shared__ __align__(16) unsigned short b_hi[64 * APITCH], b_lo[64 * APITCH];
    const int tid = threadIdx.x;
    const int bx = blockIdx.x;
    const int mt = bx >> 3, ntile = bx & 7;
    const int wv = tid >> 6, lane = tid & 63;
    const int srow = tid >> 2, skseg = (tid & 3) * 8;
    const int m = lane & 15;
    const int ko = (lane >> 4) * 8;

    f32x4 ahh[4], ahl[4], alh[4];
#pragma unroll
    for (int i = 0; i < 4; i++) { ahh[i] = (f32x4)0.f; ahl[i] = (f32x4)0.f; alh[i] = (f32x4)0.f; }

    for (int kt = 0; kt < 16; ++kt) {
        {
            float fa[8], fb[8];
            const float* pa = A + (size_t)(mt * 64 + srow) * I_DIM + kt * 32 + skseg;
            *(float4*)(fa)     = *(const float4*)(pa);
            *(float4*)(fa + 4) = *(const float4*)(pa + 4);
            const float* pb = W + (size_t)(ntile * 64 + srow) * I_DIM + kt * 32 + skseg;
            *(float4*)(fb)     = *(const float4*)(pb);
            *(float4*)(fb + 4) = *(const float4*)(pb + 4);
            short8 hi, lo;
#pragma unroll
            for (int i = 0; i < 8; i++) {
                unsigned short h = f2bf(fa[i]);
                hi[i] = (short)h; lo[i] = (short)f2bf(fa[i] - bf2f(h));
            }
            *(short8*)&a_hi[srow * APITCH + skseg] = hi;
            *(short8*)&a_lo[srow * APITCH + skseg] = lo;
#pragma unroll
            for (int i = 0; i < 8; i++) {
                unsigned short h = f2bf(fb[i]);
                hi[i] = (short)h; lo[i] = (short)f2bf(fb[i] - bf2f(h));
            }
            *(short8*)&b_hi[srow * APITCH + skseg] = hi;
            *(short8*)&b_lo[srow * APITCH + skseg] = lo;
        }
        __syncthreads();
        short8 vah = *(const short8*)&a_hi[(wv * 16 + m) * APITCH + ko];
        short8 val = *(const short8*)&a_lo[(wv * 16 + m) * APITCH + ko];
#pragma unroll
        for (int ns = 0; ns < 4; ++ns) {
            short8 vbh = *(const short8*)&b_hi[(ns * 16 + m) * APITCH + ko];
            short8 vbl = *(const short8*)&b_lo[(ns * 16 + m) * APITCH + ko];
            ahh[ns] = __builtin_amdgcn_mfma_f32_16x16x32_bf16(vah, vbh, ahh[ns], 0, 0, 0);
            ahl[ns] = __builtin_amdgcn_mfma_f32_16x16x32_bf16(vah, vbl, ahl[ns], 0, 0, 0);
            alh[ns] = __builtin_amdgcn_mfma_f32_16x16x32_bf16(val, vbh, alh[ns], 0, 0, 0);
        }
        __syncthreads();
    }
#pragma unroll
    for (int ns = 0; ns < 4; ++ns) {
#pragma unroll
        for (int rr = 0; rr < 4; ++rr) {
            int rowd = wv * 16 + (lane >> 4) * 4 + rr;
            int cold = ntile * 64 + ns * 16 + (lane & 15);
            float v = ahh[ns][rr] + ahl[ns][rr] + alh[ns][rr] + bias[cold];
            C[(size_t)(mt * 64 + rowd) * H_DIM + cold] = v;
        }
    }
}

// ---------------------------------------------------------------------------
// Recurrent persistent kernel. 32 WGs = 4 groups (16 batch rows) x 8 col
// slices. All cross-WG traffic is RELAXED device-scope (sc0 sc1) — never a
// cache flush. h exchanged as pre-packed bf16 hi/lo planes; MFMA frags read
// straight from LDS with ds_read_b128. xn/xzr prefetched under the spin.
// ---------------------------------------------------------------------------
__global__ __launch_bounds__(256, 1) void rnn_kernel(
    const float* __restrict__ h0,
    const unsigned int* __restrict__ xzr,
    const float* __restrict__ zuw, const float* __restrict__ ruw,
    const float* __restrict__ zub, const float* __restrict__ rub,
    const float* __restrict__ huw, const float* __restrict__ hub,
    float* __restrict__ out,
    char* __restrict__ xbuf, unsigned int* __restrict__ flags)
{
    __shared__ __align__(16) unsigned short hs_hi[16 * 512], hs_lo[16 * 512];
    __shared__ float zu[512], ru[512];
    __shared__ float zg[16], rg[16];

    const int tid = threadIdx.x;
    const int bid = blockIdx.x;
    const int g = bid >> 3, js = bid & 7;
    const int wv = tid >> 6, lane = tid & 63;
    const int quad = lane >> 4, am = lane & 15;
    const int col = js * 64 + wv * 16 + am;
    const int ko = quad * 8;
    const int gr = tid >> 4, gs = tid & 15;

    for (int i = tid; i < 512; i += 256) { zu[i] = zuw[i]; ru[i] = ruw[i]; }
    const float zbias = zub[0], rbias = rub[0];
    const float hubl = hub[col];

    // persistent recurrent weights: bf16 hi/lo B-fragments (128 VGPRs)
    short8 wh[16], wl[16];
#pragma unroll
    for (int kt = 0; kt < 16; ++kt) {
        float f[8];
        const float* p = huw + (size_t)col * H_DIM + kt * 32 + ko;
        *(float4*)(f)     = *(const float4*)(p);
        *(float4*)(f + 4) = *(const float4*)(p + 4);
#pragma unroll
        for (int i = 0; i < 8; i++) {
            unsigned short h = f2bf(f[i]);
            wh[kt][i] = (short)h;
            wl[kt][i] = (short)f2bf(f[i] - bf2f(h));
        }
    }

    // init LDS with packed h0
#pragma unroll
    for (int i = 0; i < 8; i++) {
        int idx = tid * 4 + i * 1024;
        int row = idx >> 9, k = idx & 511;
        float4 f = *(const float4*)(h0 + (size_t)(g * 16 + row) * H_DIM + k);
        float fa[4] = {f.x, f.y, f.z, f.w};
        unsigned int h_[4], l_[4];
#pragma unroll
        for (int j = 0; j < 4; j++) {
            h_[j] = f2bf(fa[j]);
            l_[j] = f2bf(fa[j] - bf2f((unsigned short)h_[j]));
        }
        int a = SW16(row, k);
        uint2 hv = { h_[0] | (h_[1] << 16), h_[2] | (h_[3] << 16) };
        uint2 lv = { l_[0] | (l_[1] << 16), l_[2] | (l_[3] << 16) };
        *(uint2*)&hs_hi[a] = hv;
        *(uint2*)&hs_lo[a] = lv;
    }
    float hkeep[4];
#pragma unroll
    for (int rr = 0; rr < 4; ++rr)
        hkeep[rr] = h0[(size_t)(g * 16 + quad * 4 + rr) * H_DIM + col];
    __syncthreads();

    // prefetch registers for step t: xn (4 rows) + packed xz/xr word
    float xnv0, xnv1, xnv2, xnv3;
    unsigned int zrw;
#define PREFETCH(tt) do {                                                     \
        const float* xp_ = out + (size_t)(tt) * BH +                          \
                           (size_t)(g * 16 + quad * 4) * H_DIM + col;         \
        ld32f(xnv0, xp_);        ld32f(xnv1, xp_ + H_DIM);                    \
        ld32f(xnv2, xp_ + 2 * H_DIM); ld32f(xnv3, xp_ + 3 * H_DIM);           \
        ld32u(zrw, xzr + (tt) * B_DIM + g * 16 + gr);                         \
    } while (0)
    PREFETCH(0);

    for (int t = 0; t < T_DIM; ++t) {
        // --- B: gates (uses prefetched zrw; LDS holds h_{t-1}) ------------
        asm volatile("s_waitcnt vmcnt(0)"
                     : "+v"(xnv0), "+v"(xnv1), "+v"(xnv2), "+v"(xnv3), "+v"(zrw)
                     :: "memory");
        float pz = 0.f, pr = 0.f;
#pragma unroll
        for (int i = 0; i < 8; i++) {
            int k = gs * 4 + i * 64;
            int a = SW16(gr, k);
            uint2 hw = *(const uint2*)&hs_hi[a];
            uint2 lw = *(const uint2*)&hs_lo[a];
            float4 zv = *(const float4*)&zu[k];
            float4 rv = *(const float4*)&ru[k];
            float h0f = uasf(hw.x << 16) + uasf(lw.x << 16);
            float h1f = uasf(hw.x & 0xFFFF0000u) + uasf(lw.x & 0xFFFF0000u);
            float h2f = uasf(hw.y << 16) + uasf(lw.y << 16);
            float h3f = uasf(hw.y & 0xFFFF0000u) + uasf(lw.y & 0xFFFF0000u);
            pz += h0f * zv.x + h1f * zv.y + h2f * zv.z + h3f * zv.w;
            pr += h0f * rv.x + h1f * rv.y + h2f * rv.z + h3f * rv.w;
        }
#pragma unroll
        for (int off = 8; off > 0; off >>= 1) {
            pz += __shfl_xor(pz, off);
            pr += __shfl_xor(pr, off);
        }
        if (gs == 0) {
            float xzf = __half2float(__ushort_as_half((unsigned short)(zrw >> 16)));
            float xrf = __half2float(__ushort_as_half((unsigned short)(zrw & 0xFFFFu)));
            zg[gr] = 1.f / (1.f + __expf(-(xzf + pz + zbias)));
            rg[gr] = 1.f / (1.f + __expf(-(xrf + pr + rbias)));
        }
        __syncthreads();

        // --- D: h @ h_u_w^T slice (bf16x3, frags direct from LDS) ---------
        f32x4 hh = (f32x4)0.f, hl = (f32x4)0.f, lh = (f32x4)0.f;
#pragma unroll
        for (int kt = 0; kt < 16; ++kt) {
            short8 ah = *(const short8*)&hs_hi[SW16(am, kt * 32 + ko)];
            short8 al = *(const short8*)&hs_lo[SW16(am, kt * 32 + ko)];
            hh = __builtin_amdgcn_mfma_f32_16x16x32_bf16(ah, wh[kt], hh, 0, 0, 0);
            hl = __builtin_amdgcn_mfma_f32_16x16x32_bf16(ah, wl[kt], hl, 0, 0, 0);
            lh = __builtin_amdgcn_mfma_f32_16x16x32_bf16(al, wh[kt], lh, 0, 0, 0);
        }

        // --- E: epilogue + packed h store (relaxed coherent) --------------
        float xn_a[4] = {xnv0, xnv1, xnv2, xnv3};
        float* op = out + (size_t)t * BH;
        char* xb = xbuf + ((size_t)(((t & 1) * 4) + g)) * 32768;
        unsigned short* bhp = (unsigned short*)xb;
        unsigned short* blp = (unsigned short*)(xb + 16384);
#pragma unroll
        for (int rr = 0; rr < 4; ++rr) {
            int rl = quad * 4 + rr;
            float gemm = hh[rr] + hl[rr] + lh[rr] + hubl;
            float x2 = xn_a[rr] + gemm * rg[rl];
            x2 = fminf(fmaxf(x2, -30.f), 30.f);
            float e = __expf(2.f * x2);
            float ntv = (e - 1.f) / (e + 1.f);
            float hv = (1.f - zg[rl]) * ntv + zg[rl] * hkeep[rr];
            op[(size_t)(g * 16 + rl) * H_DIM + col] = hv;
            unsigned short hu = f2bf(hv);
            unsigned short lu = f2bf(hv - bf2f(hu));
            __hip_atomic_store(&bhp[rl * 512 + col], hu, __ATOMIC_RELAXED, __HIP_MEMORY_SCOPE_AGENT);
            __hip_atomic_store(&blp[rl * 512 + col], lu, __ATOMIC_RELAXED, __HIP_MEMORY_SCOPE_AGENT);
            hkeep[rr] = hv;
        }
        asm volatile("s_waitcnt vmcnt(0)" ::: "memory");  // drain this wave's stores
        __syncthreads();                                   // all waves drained
        if (tid == 0)
            __hip_atomic_store(&flags[g * 8 + js], (unsigned int)(t + 1),
                               __ATOMIC_RELAXED, __HIP_MEMORY_SCOPE_AGENT);
        if (t == T_DIM - 1) break;

        // --- prefetch next step's xn/xzr (hides under the spin) -----------
        PREFETCH(t + 1);

        // --- H: lane-parallel relaxed flag poll ---------------------------
        if (lane < 8) {
            const unsigned int* fp = flags + g * 8 + lane;
            while (__hip_atomic_load(fp, __ATOMIC_RELAXED, __HIP_MEMORY_SCOPE_AGENT)
                   < (unsigned int)(t + 1))
                __builtin_amdgcn_s_sleep(1);
        }

        // --- J: batched coherent load of packed h_t -> LDS ----------------
        const char* src = xbuf + ((size_t)(((t & 1) * 4) + g)) * 32768 + tid * 16;
        uint4 v[8];
#pragma unroll
        for (int i = 0; i < 7; i++) ld128_coh(v[i], src + i * 4096);
        ld128_coh_wait(v[7], src + 7 * 4096);  // drains all 8 (vmcnt counts the queue)
#pragma unroll
        for (int i = 0; i < 8; i++) {
            int usidx = tid * 8 + (i & 3) * 2048;
            int row = usidx >> 9, ku = usidx & 511;
            unsigned short* dst = (i < 4) ? hs_hi : hs_lo;
            *(uint4*)&dst[SW16(row, ku)] = v[i];
        }
        __syncthreads();
    }

    // hidden_final
#pragma unroll
    for (int rr = 0; rr < 4; ++rr)
        out[TBH + (size_t)(g * 16 + quad * 4 + rr) * H_DIM + col] = hkeep[rr];
#undef PREFETCH
}

extern "C" void kernel_launch(void* const* d_in, const int* in_sizes, int n_in,
                              void* d_out, int out_size, void* d_ws, size_t ws_size,
                              hipStream_t stream)
{
    const float* input  = (const float*)d_in[0];
    const float* hidden = (const float*)d_in[1];
    const float* zt_w_w = (const float*)d_in[2];
    const float* zt_w_b = (const float*)d_in[3];
    const float* zt_u_w = (const float*)d_in[4];
    const float* zt_u_b = (const float*)d_in[5];
    const float* rt_w_w = (const float*)d_in[6];
    const float* rt_w_b = (const float*)d_in[7];
    const float* rt_u_w = (const float*)d_in[8];
    const float* rt_u_b = (const float*)d_in[9];
    const float* h_w_w  = (const float*)d_in[10];
    const float* h_w_b  = (const float*)d_in[11];
    const float* h_u_w  = (const float*)d_in[12];
    const float* h_u_b  = (const float*)d_in[13];
    float* out = (float*)d_out;

    // ws: [0,4K) flags | [4K, 4K+256K) xbuf (2 slots x 4 groups x 32KB)
    //     | [+, +128K) packed f16 xz/xr.  Total 388KB.
    unsigned int* flags = (unsigned int*)d_ws;
    char* xbuf = (char*)d_ws + 4096;
    unsigned int* xzr = (unsigned int*)((char*)d_ws + 4096 + 262144);

    xzr_kernel<<<dim3(8192), dim3(256), 0, stream>>>(input, zt_w_w, zt_w_b,
                                                     rt_w_w, rt_w_b, xzr, flags);
    xn_gemm_kernel<<<dim3(4096), dim3(256), 0, stream>>>(input, h_w_w, h_w_b, out);
    rnn_kernel<<<dim3(32), dim3(256), 0, stream>>>(hidden, xzr, zt_u_w, rt_u_w,
                                                   zt_u_b, rt_u_b, h_u_w, h_u_b,
                                                   out, xbuf, flags);
}